// Round 1
// baseline (131.660 us; speedup 1.0000x reference)
//
#include <hip/hip_runtime.h>
#include <hip/hip_bf16.h>

typedef __bf16 bf16_t;
typedef __bf16 bf16x8 __attribute__((ext_vector_type(8)));
typedef float f32x4 __attribute__((ext_vector_type(4)));

static __device__ __forceinline__ bf16_t to_bf16(float f) { return (bf16_t)f; }

// ---------------- convert x: f32 -> bf16 (8 elems/thread) ----------------
__global__ void k_convert_x(const float* __restrict__ src, bf16_t* __restrict__ dst, int n8) {
  int i = blockIdx.x * blockDim.x + threadIdx.x;
  if (i >= n8) return;
  const float4* s = reinterpret_cast<const float4*>(src) + (size_t)i * 2;
  float4 a = s[0], b = s[1];
  bf16x8 v;
  v[0]=(bf16_t)a.x; v[1]=(bf16_t)a.y; v[2]=(bf16_t)a.z; v[3]=(bf16_t)a.w;
  v[4]=(bf16_t)b.x; v[5]=(bf16_t)b.y; v[6]=(bf16_t)b.z; v[7]=(bf16_t)b.w;
  reinterpret_cast<bf16x8*>(dst)[i] = v;
}

// ------------- transpose+convert: src f32 [512][Nc] -> dst bf16 [Nc][512] -------------
__global__ void k_transpose_cvt(const float* __restrict__ src, bf16_t* __restrict__ dst, int Nc) {
  __shared__ bf16_t tile[64 * 72];
  const int n0 = blockIdx.x * 64, k0 = blockIdx.y * 64;
  const int t = threadIdx.x;
  #pragma unroll
  for (int it = 0; it < 16; ++it) {
    int c = t + it * 256;
    int kl = c >> 6, nl = c & 63;
    tile[kl * 72 + nl] = to_bf16(src[(size_t)(k0 + kl) * Nc + n0 + nl]);
  }
  __syncthreads();
  #pragma unroll
  for (int it = 0; it < 16; ++it) {
    int c = t + it * 256;
    int nl = c >> 6, kl = c & 63;
    dst[(size_t)(n0 + nl) * 512 + k0 + kl] = tile[kl * 72 + nl];
  }
}

// ---------------- fused projection GEMM: [4096x512] @ [512x2048] ----------------
// BT is B^T layout [2048][512].  Epilogue scatters q (scaled), k, v^T, gates.
__global__ __launch_bounds__(256) void k_gemm_proj(
    const bf16_t* __restrict__ A,   // x_bf [4096][512]
    const bf16_t* __restrict__ BT,  // WcatT [2048][512]
    const float*  __restrict__ bg,  // [512]
    bf16_t* __restrict__ qo,        // [16][2048][64]
    bf16_t* __restrict__ ko,        // [16][2048][64]
    bf16_t* __restrict__ vto,       // [16][64][2048]
    float*  __restrict__ go)        // [4096][512]
{
  __shared__ __align__(16) bf16_t lA[128 * 72];
  __shared__ __align__(16) bf16_t lB[128 * 72];
  const int t = threadIdx.x;
  const int w = t >> 6, lane = t & 63, lr = lane & 15, lg = lane >> 4;
  const int wr = w >> 1, wc = w & 1;
  const int m0 = blockIdx.y * 128, n0 = blockIdx.x * 128;
  f32x4 acc[4][4] = {};
  for (int k0 = 0; k0 < 512; k0 += 64) {
    __syncthreads();
    #pragma unroll
    for (int it = 0; it < 4; ++it) {
      int c = t + it * 256;
      int row = c >> 3, cc = c & 7;
      *reinterpret_cast<bf16x8*>(&lA[row * 72 + cc * 8]) =
          *reinterpret_cast<const bf16x8*>(&A[(size_t)(m0 + row) * 512 + k0 + cc * 8]);
      *reinterpret_cast<bf16x8*>(&lB[row * 72 + cc * 8]) =
          *reinterpret_cast<const bf16x8*>(&BT[(size_t)(n0 + row) * 512 + k0 + cc * 8]);
    }
    __syncthreads();
    #pragma unroll
    for (int kk = 0; kk < 2; ++kk) {
      bf16x8 af[4], bfm[4];
      #pragma unroll
      for (int mf = 0; mf < 4; ++mf)
        af[mf] = *reinterpret_cast<const bf16x8*>(&lA[(wr*64 + mf*16 + lr) * 72 + kk*32 + lg*8]);
      #pragma unroll
      for (int nf = 0; nf < 4; ++nf)
        bfm[nf] = *reinterpret_cast<const bf16x8*>(&lB[(wc*64 + nf*16 + lr) * 72 + kk*32 + lg*8]);
      #pragma unroll
      for (int mf = 0; mf < 4; ++mf)
        #pragma unroll
        for (int nf = 0; nf < 4; ++nf)
          acc[mf][nf] = __builtin_amdgcn_mfma_f32_16x16x32_bf16(af[mf], bfm[nf], acc[mf][nf], 0, 0, 0);
    }
  }
  const int seg = n0 >> 9;  // 0:q 1:k 2:v 3:g  (uniform per block)
  #pragma unroll
  for (int mf = 0; mf < 4; ++mf) {
    #pragma unroll
    for (int nf = 0; nf < 4; ++nf) {
      #pragma unroll
      for (int r = 0; r < 4; ++r) {
        int rm = m0 + wr*64 + mf*16 + lg*4 + r;   // global M (b*2048+n)
        int cn = n0 + wc*64 + nf*16 + lr;          // global N
        float v = acc[mf][nf][r];
        int b = rm >> 11, n = rm & 2047;
        int c = cn & 511;
        if (seg == 0) {
          int h = c >> 6, dh = c & 63;
          qo[((size_t)(b*8 + h) * 2048 + n) * 64 + dh] = to_bf16(v * 0.125f);
        } else if (seg == 1) {
          int h = c >> 6, dh = c & 63;
          ko[((size_t)(b*8 + h) * 2048 + n) * 64 + dh] = to_bf16(v);
        } else if (seg == 2) {
          int h = c >> 6, dh = c & 63;
          vto[((size_t)(b*8 + h) * 64 + dh) * 2048 + n] = to_bf16(v);
        } else {
          float z = v + bg[c];
          go[(size_t)rm * 512 + c] = 1.0f / (1.0f + __expf(-z));
        }
      }
    }
  }
}

// ---------------- flash attention with additive bias + gating epilogue ----------------
__global__ __launch_bounds__(256) void k_attn(
    const bf16_t* __restrict__ q,    // [16][2048][64] (pre-scaled)
    const bf16_t* __restrict__ kb,   // [16][2048][64]
    const bf16_t* __restrict__ vt,   // [16][64][2048]
    const float*  __restrict__ bias, // [8][2048][2048]
    const float*  __restrict__ gates,// [4096][512]
    bf16_t* __restrict__ ao)         // [4096][512]
{
  __shared__ __align__(16) bf16_t lK[64 * 72];
  __shared__ __align__(16) bf16_t lV[64 * 72];
  __shared__ __align__(16) bf16_t lP[4][16 * 72];
  const int t = threadIdx.x, w = t >> 6, lane = t & 63, lr = lane & 15, lg = lane >> 4;
  const int bh = blockIdx.y, b = bh >> 3, h = bh & 7;
  const int i0 = blockIdx.x * 64, ib = i0 + w * 16;

  bf16x8 aq[2];
  const bf16_t* qp = q + ((size_t)bh * 2048 + ib + lr) * 64;
  aq[0] = *reinterpret_cast<const bf16x8*>(qp + lg * 8);
  aq[1] = *reinterpret_cast<const bf16x8*>(qp + 32 + lg * 8);

  float m_r[4] = {-1e30f, -1e30f, -1e30f, -1e30f};
  float l_r[4] = {0.f, 0.f, 0.f, 0.f};
  f32x4 accO[4] = {};

  const float* bias_p = bias + (size_t)h * 2048 * 2048 + (size_t)(ib + lg * 4) * 2048 + lr;
  const bf16_t* kp = kb + (size_t)bh * 2048 * 64;
  const bf16_t* vp = vt + (size_t)bh * 64 * 2048;

  for (int jt = 0; jt < 32; ++jt) {
    const int j0 = jt * 64;
    float bv[4][4];
    #pragma unroll
    for (int nf = 0; nf < 4; ++nf)
      #pragma unroll
      for (int r = 0; r < 4; ++r)
        bv[nf][r] = bias_p[(size_t)r * 2048 + j0 + nf * 16];

    __syncthreads();
    #pragma unroll
    for (int it = 0; it < 2; ++it) {
      int c = t + it * 256;
      int row = c >> 3, cc = c & 7;
      *reinterpret_cast<bf16x8*>(&lK[row * 72 + cc * 8]) =
          *reinterpret_cast<const bf16x8*>(&kp[(size_t)(j0 + row) * 64 + cc * 8]);
      *reinterpret_cast<bf16x8*>(&lV[row * 72 + cc * 8]) =
          *reinterpret_cast<const bf16x8*>(&vp[(size_t)row * 2048 + j0 + cc * 8]);
    }
    __syncthreads();

    // S = Q K^T  (16 x 64 per wave), f32 acc
    f32x4 s[4] = {};
    #pragma unroll
    for (int kk = 0; kk < 2; ++kk) {
      #pragma unroll
      for (int nf = 0; nf < 4; ++nf) {
        bf16x8 bf = *reinterpret_cast<const bf16x8*>(&lK[(nf*16 + lr) * 72 + kk*32 + lg*8]);
        s[nf] = __builtin_amdgcn_mfma_f32_16x16x32_bf16(aq[kk], bf, s[nf], 0, 0, 0);
      }
    }
    #pragma unroll
    for (int nf = 0; nf < 4; ++nf)
      #pragma unroll
      for (int r = 0; r < 4; ++r)
        s[nf][r] += bv[nf][r];

    // online softmax (rows owned per lg-group; reduce across 16-lane group)
    #pragma unroll
    for (int r = 0; r < 4; ++r) {
      float rmx = fmaxf(fmaxf(s[0][r], s[1][r]), fmaxf(s[2][r], s[3][r]));
      rmx = fmaxf(rmx, __shfl_xor(rmx, 1));
      rmx = fmaxf(rmx, __shfl_xor(rmx, 2));
      rmx = fmaxf(rmx, __shfl_xor(rmx, 4));
      rmx = fmaxf(rmx, __shfl_xor(rmx, 8));
      float mnew = fmaxf(m_r[r], rmx);
      float corr = __expf(m_r[r] - mnew);
      m_r[r] = mnew;
      float rs = 0.f;
      #pragma unroll
      for (int nf = 0; nf < 4; ++nf) {
        float p = __expf(s[nf][r] - mnew);
        s[nf][r] = p;
        rs += p;
      }
      rs += __shfl_xor(rs, 1); rs += __shfl_xor(rs, 2);
      rs += __shfl_xor(rs, 4); rs += __shfl_xor(rs, 8);
      l_r[r] = l_r[r] * corr + rs;
      #pragma unroll
      for (int df = 0; df < 4; ++df) accO[df][r] *= corr;
    }

    // P -> per-wave LDS (D-layout write), re-read in A-layout
    #pragma unroll
    for (int nf = 0; nf < 4; ++nf)
      #pragma unroll
      for (int r = 0; r < 4; ++r)
        lP[w][(lg*4 + r) * 72 + nf*16 + lr] = to_bf16(s[nf][r]);

    #pragma unroll
    for (int kk = 0; kk < 2; ++kk) {
      bf16x8 pa = *reinterpret_cast<const bf16x8*>(&lP[w][lr * 72 + kk*32 + lg*8]);
      #pragma unroll
      for (int df = 0; df < 4; ++df) {
        bf16x8 bv8 = *reinterpret_cast<const bf16x8*>(&lV[(df*16 + lr) * 72 + kk*32 + lg*8]);
        accO[df] = __builtin_amdgcn_mfma_f32_16x16x32_bf16(pa, bv8, accO[df], 0, 0, 0);
      }
    }
  }

  // epilogue: normalize, gate, store bf16
  #pragma unroll
  for (int r = 0; r < 4; ++r) {
    float inv = 1.0f / l_r[r];
    int ig = ib + lg*4 + r;
    #pragma unroll
    for (int df = 0; df < 4; ++df) {
      int dg = h*64 + df*16 + lr;
      float gate = gates[(size_t)(b*2048 + ig) * 512 + dg];
      ao[(size_t)(b*2048 + ig) * 512 + dg] = to_bf16(accO[df][r] * inv * gate);
    }
  }
}

// ---------------- output GEMM: [4096x512] @ [512x512] + bo -> f32 ----------------
__global__ __launch_bounds__(256) void k_gemm_out(
    const bf16_t* __restrict__ A,   // ao [4096][512]
    const bf16_t* __restrict__ BT,  // WoT [512][512]
    const float*  __restrict__ bo,  // [512]
    float* __restrict__ out)        // [4096][512]
{
  __shared__ __align__(16) bf16_t lA[128 * 72];
  __shared__ __align__(16) bf16_t lB[128 * 72];
  const int t = threadIdx.x;
  const int w = t >> 6, lane = t & 63, lr = lane & 15, lg = lane >> 4;
  const int wr = w >> 1, wc = w & 1;
  const int m0 = blockIdx.y * 128, n0 = blockIdx.x * 128;
  f32x4 acc[4][4] = {};
  for (int k0 = 0; k0 < 512; k0 += 64) {
    __syncthreads();
    #pragma unroll
    for (int it = 0; it < 4; ++it) {
      int c = t + it * 256;
      int row = c >> 3, cc = c & 7;
      *reinterpret_cast<bf16x8*>(&lA[row * 72 + cc * 8]) =
          *reinterpret_cast<const bf16x8*>(&A[(size_t)(m0 + row) * 512 + k0 + cc * 8]);
      *reinterpret_cast<bf16x8*>(&lB[row * 72 + cc * 8]) =
          *reinterpret_cast<const bf16x8*>(&BT[(size_t)(n0 + row) * 512 + k0 + cc * 8]);
    }
    __syncthreads();
    #pragma unroll
    for (int kk = 0; kk < 2; ++kk) {
      bf16x8 af[4], bfm[4];
      #pragma unroll
      for (int mf = 0; mf < 4; ++mf)
        af[mf] = *reinterpret_cast<const bf16x8*>(&lA[(wr*64 + mf*16 + lr) * 72 + kk*32 + lg*8]);
      #pragma unroll
      for (int nf = 0; nf < 4; ++nf)
        bfm[nf] = *reinterpret_cast<const bf16x8*>(&lB[(wc*64 + nf*16 + lr) * 72 + kk*32 + lg*8]);
      #pragma unroll
      for (int mf = 0; mf < 4; ++mf)
        #pragma unroll
        for (int nf = 0; nf < 4; ++nf)
          acc[mf][nf] = __builtin_amdgcn_mfma_f32_16x16x32_bf16(af[mf], bfm[nf], acc[mf][nf], 0, 0, 0);
    }
  }
  #pragma unroll
  for (int mf = 0; mf < 4; ++mf) {
    #pragma unroll
    for (int nf = 0; nf < 4; ++nf) {
      #pragma unroll
      for (int r = 0; r < 4; ++r) {
        int rm = m0 + wr*64 + mf*16 + lg*4 + r;
        int cn = n0 + wc*64 + nf*16 + lr;
        out[(size_t)rm * 512 + cn] = acc[mf][nf][r] + bo[cn];
      }
    }
  }
}

extern "C" void kernel_launch(void* const* d_in, const int* in_sizes, int n_in,
                              void* d_out, int out_size, void* d_ws, size_t ws_size,
                              hipStream_t stream) {
  const float* x    = (const float*)d_in[0];
  const float* bias = (const float*)d_in[1];
  const float* Wq   = (const float*)d_in[2];
  const float* Wkv  = (const float*)d_in[3];
  const float* Wo   = (const float*)d_in[4];
  const float* bo   = (const float*)d_in[5];
  const float* Wg   = (const float*)d_in[6];
  const float* bg   = (const float*)d_in[7];
  float* out = (float*)d_out;

  char* ws = (char*)d_ws;
  const size_t MB = 1024 * 1024;
  bf16_t* x_bf  = (bf16_t*)(ws + 0 * MB);   // 4 MB  [4096][512]
  bf16_t* WcatT = (bf16_t*)(ws + 4 * MB);   // 2 MB  [2048][512]
  bf16_t* WoT   = (bf16_t*)(ws + 6 * MB);   // 0.5MB [512][512]
  bf16_t* q_bf  = (bf16_t*)(ws + 7 * MB);   // 4 MB  [16][2048][64]
  bf16_t* k_bf  = (bf16_t*)(ws + 11 * MB);  // 4 MB  [16][2048][64]
  bf16_t* vt_bf = (bf16_t*)(ws + 15 * MB);  // 4 MB  [16][64][2048]
  float*  g_f32 = (float*) (ws + 19 * MB);  // 8 MB  [4096][512]
  bf16_t* ao_bf = (bf16_t*)(ws + 27 * MB);  // 4 MB  [4096][512]   (total 31 MB)

  k_convert_x<<<1024, 256, 0, stream>>>(x, x_bf, 2097152 / 8);
  k_transpose_cvt<<<dim3(8, 8),  256, 0, stream>>>(Wq,  WcatT,               512);
  k_transpose_cvt<<<dim3(16, 8), 256, 0, stream>>>(Wkv, WcatT + 512 * 512,  1024);
  k_transpose_cvt<<<dim3(8, 8),  256, 0, stream>>>(Wg,  WcatT + 1536 * 512,  512);
  k_transpose_cvt<<<dim3(8, 8),  256, 0, stream>>>(Wo,  WoT,                 512);
  k_gemm_proj<<<dim3(16, 32), 256, 0, stream>>>(x_bf, WcatT, bg, q_bf, k_bf, vt_bf, g_f32);
  k_attn<<<dim3(32, 16), 256, 0, stream>>>(q_bf, k_bf, vt_bf, bias, g_f32, ao_bf);
  k_gemm_out<<<dim3(4, 32), 256, 0, stream>>>(ao_bf, WoT, bo, out);
}